// Round 6
// baseline (1942.488 us; speedup 1.0000x reference)
//
#include <hip/hip_runtime.h>
#include <math.h>

// SRNN: S=16 steps, N=32768 nodes, E=131072 spatial edges.
// f16 MFMA gate GEMMs, B-resident weights, c-state staged via LDS (kills the
// per-tile global-latency stall), output projection fused into node epilogue.
// h-states f16, c-states fp32.

#define S_LEN 16
#define NN 32768
#define EE 131072

typedef _Float16 f16;
typedef _Float16 f16x8 __attribute__((ext_vector_type(8)));
typedef float f32x4 __attribute__((ext_vector_type(4)));

__device__ __forceinline__ float fsigmoid(float x) {
    return __builtin_amdgcn_rcpf(1.0f + __builtin_amdgcn_exp2f(-1.44269504f * x));
}
__device__ __forceinline__ float ftanh(float x) {
    const float e = __builtin_amdgcn_exp2f(2.88539008f * x);
    return 1.0f - 2.0f * __builtin_amdgcn_rcpf(e + 1.0f);
}

__device__ __forceinline__ unsigned int pk2(float a, float b) {
    union { f16 h[2]; unsigned int u; } x;
    x.h[0] = (f16)a; x.h[1] = (f16)b;
    return x.u;
}

__device__ __forceinline__ f16x8 ld_frag16(const void* p) {
    union { uint4 v; f16x8 f; } x;
    x.v = *(const uint4*)p;
    return x.f;
}

// ---------------- fused edge LSTM (temporal + spatial), H=64 ----------------
// TR=64 rows/block, 4 waves. Wave wv owns hidden cols [16wv,16wv+16) for all
// 4 gates; B-fragments resident. c staged via LDS (padded stride 68).
__global__ __launch_bounds__(256) void edge_lstm_fused(
    const float* __restrict__ xT, const float* __restrict__ xS,
    const float* __restrict__ t_enc_w, const float* __restrict__ t_enc_b,
    const float* __restrict__ s_enc_w, const float* __restrict__ s_enc_b,
    const f16* __restrict__ WtT, const f16* __restrict__ WtS,
    const float* __restrict__ biasT, const float* __restrict__ biasS,
    f16* __restrict__ hT, float* __restrict__ cT,
    f16* __restrict__ hS, float* __restrict__ cS)
{
    constexpr int H = 64, K = 128, KSTEPS = 4, ROWB = 256, TR = 64;
    __shared__ __align__(16) char Xls[TR * ROWB];   // 16 KB
    __shared__ __align__(16) float cls[TR * 68];    // 17.4 KB (pad 64->68)

    const int bT = NN / TR;
    const bool isT = (int)blockIdx.x < bT;
    const int row0 = (isT ? blockIdx.x : blockIdx.x - bT) * TR;
    const float* xf    = isT ? xT : xS;
    const float* enc_w = isT ? t_enc_w : s_enc_w;
    const float* enc_b = isT ? t_enc_b : s_enc_b;
    const f16*   Wt    = isT ? WtT : WtS;
    const float* bias  = isT ? biasT : biasS;
    f16*   h = isT ? hT : hS;
    float* c = isT ? cT : cS;

    const int t = threadIdx.x;
    const int wv = t >> 6, l = t & 63;
    const int lane15 = l & 15, kgrp = l >> 4;

    // B fragments: resident
    f16x8 bfrag[4][KSTEPS];
    #pragma unroll
    for (int q = 0; q < 4; ++q) {
        const int colq = q * H + wv * 16 + lane15;
        const f16* bp = Wt + (size_t)colq * K + kgrp * 8;
        #pragma unroll
        for (int ks = 0; ks < KSTEPS; ++ks)
            bfrag[q][ks] = ld_frag16(bp + ks * 32);
    }

    // stage c (coalesced global -> padded LDS)
    {
        const int r = t >> 2, q = t & 3;
        const float* cp = &c[(size_t)(row0 + r) * H + q * 16];
        float* dp = &cls[r * 68 + q * 16];
        #pragma unroll
        for (int j = 0; j < 4; ++j)
            *(float4*)(dp + 4 * j) = *(const float4*)(cp + 4 * j);
    }

    // stage x-enc (cols 0..63)
    for (int i = t; i < TR * (H / 2); i += 256) {
        const int r = i / (H / 2), j2 = (i % (H / 2)) * 2;
        const int grow = row0 + r;
        const float x0 = xf[grow * 2 + 0];
        const float x1 = xf[grow * 2 + 1];
        const float e0 = fmaxf(0.f, fmaf(x0, enc_w[j2],     fmaf(x1, enc_w[H + j2],     enc_b[j2])));
        const float e1 = fmaxf(0.f, fmaf(x0, enc_w[j2 + 1], fmaf(x1, enc_w[H + j2 + 1], enc_b[j2 + 1])));
        const int byte = r * ROWB + ((j2 * 2) ^ ((r & 7) << 4));
        *(unsigned int*)(Xls + byte) = pk2(e0, e1);
    }
    // stage h (cols 64..127)
    for (int i = t; i < TR * (H / 4); i += 256) {
        const int r = i / (H / 4), j4 = (i % (H / 4)) * 4;
        const uint2 v = *(const uint2*)&h[(size_t)(row0 + r) * H + j4];
        const int byte = r * ROWB + ((H * 2 + j4 * 2) ^ ((r & 7) << 4));
        *(uint2*)(Xls + byte) = v;
    }
    __syncthreads();

    const int col = wv * 16 + lane15;
    const float bi = bias[0 * H + col];
    const float bf = bias[1 * H + col];
    const float bg = bias[2 * H + col];
    const float bo = bias[3 * H + col];

    #pragma unroll
    for (int rt = 0; rt < TR / 16; ++rt) {
        const int arow = rt * 16 + lane15;
        const char* abase = Xls + arow * ROWB;
        f16x8 afrag[KSTEPS];
        #pragma unroll
        for (int ks = 0; ks < KSTEPS; ++ks) {
            const int byte = (ks * 64 + kgrp * 16) ^ ((arow & 7) << 4);
            afrag[ks] = ld_frag16(abase + byte);
        }
        f32x4 acc[4];
        #pragma unroll
        for (int q = 0; q < 4; ++q)
            #pragma unroll
            for (int r = 0; r < 4; ++r) acc[q][r] = 0.f;
        #pragma unroll
        for (int ks = 0; ks < KSTEPS; ++ks)
            #pragma unroll
            for (int q = 0; q < 4; ++q)
                acc[q] = __builtin_amdgcn_mfma_f32_16x16x32_f16(
                    afrag[ks], bfrag[q][ks], acc[q], 0, 0, 0);
        #pragma unroll
        for (int reg = 0; reg < 4; ++reg) {
            const int rl = rt * 16 + (l >> 4) * 4 + reg;
            const int grow = row0 + rl;
            const size_t off = (size_t)grow * H + col;
            const float ig = fsigmoid(acc[0][reg] + bi);
            const float fg = fsigmoid(acc[1][reg] + bf);
            const float gg = ftanh(acc[2][reg] + bg);
            const float og = fsigmoid(acc[3][reg] + bo);
            const float cold = cls[rl * 68 + col];
            const float c2 = fmaf(fg, cold, ig * gg);
            c[off] = c2;
            h[off] = (f16)(og * ftanh(c2));
        }
    }
}

// ---------------- gather + embed fused ----------------
__global__ __launch_bounds__(256) void gather_embed(
    const float* __restrict__ xn,
    const f16* __restrict__ ht, const f16* __restrict__ hs,
    const int* __restrict__ ptr, const int* __restrict__ rowidx,
    const float* __restrict__ n_enc_w, const float* __restrict__ n_enc_b,
    const f16* __restrict__ Wt_ee,   // [64][128]
    const float* __restrict__ ee_b,
    f16* __restrict__ xnode)
{
    constexpr int TR = 64;
    __shared__ __align__(16) char Xls[TR * 256];
    const int row0 = blockIdx.x * TR;
    const int t = threadIdx.x;
    const int wv = t >> 6, l = t & 63;
    const int lane15 = l & 15, kgrp = l >> 4;

    const int col = wv * 16 + lane15;
    f16x8 bfrag[4];
    {
        const f16* bp = Wt_ee + (size_t)col * 128 + kgrp * 8;
        #pragma unroll
        for (int ks = 0; ks < 4; ++ks) bfrag[ks] = ld_frag16(bp + ks * 32);
    }

    // stage ht -> K cols 0..63
    for (int i = t; i < TR * 16; i += 256) {
        const int r = i / 16, j4 = (i % 16) * 4;
        const uint2 v = *(const uint2*)&ht[(size_t)(row0 + r) * 64 + j4];
        const int byte = r * 256 + ((j4 * 2) ^ ((r & 7) << 4));
        *(uint2*)(Xls + byte) = v;
    }

    // CSR gather -> K cols 64..127 (4 threads per row, 16 f16 cols each)
    {
        const int r = t >> 2, q = t & 3;
        const int n = row0 + r;
        const int beg = ptr[n], end = ptr[n + 1];
        const unsigned int* hs32 = (const unsigned int*)hs;
        float acc[16];
        #pragma unroll
        for (int j = 0; j < 16; ++j) acc[j] = 0.f;
        for (int i = beg; i < end; ++i) {
            const int e = rowidx[i];
            const unsigned int* ep = hs32 + (size_t)e * 32 + q * 8;
            #pragma unroll
            for (int j = 0; j < 8; ++j) {
                union { unsigned int u; f16 h[2]; } v;
                v.u = ep[j];
                acc[2 * j]     += (float)v.h[0];
                acc[2 * j + 1] += (float)v.h[1];
            }
        }
        #pragma unroll
        for (int j = 0; j < 8; ++j) {
            const int byte = r * 256 + ((128 + q * 32 + j * 4) ^ ((r & 7) << 4));
            *(unsigned int*)(Xls + byte) = pk2(acc[2 * j], acc[2 * j + 1]);
        }
    }
    __syncthreads();

    const float bb = ee_b[col];
    #pragma unroll
    for (int rt = 0; rt < TR / 16; ++rt) {
        const int arow = rt * 16 + lane15;
        const char* abase = Xls + arow * 256;
        f16x8 afrag[4];
        #pragma unroll
        for (int ks = 0; ks < 4; ++ks) {
            const int byte = (ks * 64 + kgrp * 16) ^ ((arow & 7) << 4);
            afrag[ks] = ld_frag16(abase + byte);
        }
        f32x4 acc;
        #pragma unroll
        for (int r = 0; r < 4; ++r) acc[r] = 0.f;
        #pragma unroll
        for (int ks = 0; ks < 4; ++ks)
            acc = __builtin_amdgcn_mfma_f32_16x16x32_f16(afrag[ks], bfrag[ks], acc, 0, 0, 0);
        #pragma unroll
        for (int reg = 0; reg < 4; ++reg) {
            const int grow = row0 + rt * 16 + (l >> 4) * 4 + reg;
            xnode[(size_t)grow * 128 + 64 + col] = (f16)fmaxf(0.f, acc[reg] + bb);
        }
    }

    // encoder half: cols 0..63
    for (int i = t; i < TR * 32; i += 256) {
        const int r = i >> 5, j2 = (i & 31) * 2;
        const int grow = row0 + r;
        const float x = xn[grow];
        const float e0 = fmaxf(0.f, fmaf(x, n_enc_w[j2],     n_enc_b[j2]));
        const float e1 = fmaxf(0.f, fmaf(x, n_enc_w[j2 + 1], n_enc_b[j2 + 1]));
        *(unsigned int*)&xnode[(size_t)grow * 128 + j2] = pk2(e0, e1);
    }
}

// ---------------- node LSTM (H=128) + fused output projection ----------------
// TR=32 rows, 8 waves. c via LDS (stride 132). out[r] = hn[r,:]@out_w + out_b
// computed in-epilogue: quarter-wave shfl reduce -> out_part[row][wave] -> sum.
__global__ __launch_bounds__(512) void node_lstm(
    const f16* __restrict__ xin,
    const f16* __restrict__ Wt,     // [512][256]
    const float* __restrict__ bias, // [512]
    const float* __restrict__ out_w, const float* __restrict__ out_b,
    f16* __restrict__ h, float* __restrict__ c, float* __restrict__ outp)
{
    constexpr int H = 128, K = 256, KSTEPS = 8, ROWB = 512, TR = 32;
    __shared__ __align__(16) char Xls[TR * ROWB];   // 16 KB
    __shared__ __align__(16) float cls[TR * 132];   // 16.9 KB (pad 128->132)
    __shared__ float out_part[TR][8];               // 1 KB

    const int row0 = blockIdx.x * TR;
    const int t = threadIdx.x;
    const int wv = t >> 6, l = t & 63;
    const int lane15 = l & 15, kgrp = l >> 4;

    f16x8 bfrag[4][KSTEPS];
    #pragma unroll
    for (int q = 0; q < 4; ++q) {
        const int colq = q * H + wv * 16 + lane15;
        const f16* bp = Wt + (size_t)colq * K + kgrp * 8;
        #pragma unroll
        for (int ks = 0; ks < KSTEPS; ++ks)
            bfrag[q][ks] = ld_frag16(bp + ks * 32);
    }

    // stage c (coalesced -> padded LDS)
    {
        const int r = t >> 4, q = t & 15;
        const float* cp = &c[(size_t)(row0 + r) * H + q * 8];
        float* dp = &cls[r * 132 + q * 8];
        *(float4*)(dp)     = *(const float4*)(cp);
        *(float4*)(dp + 4) = *(const float4*)(cp + 4);
    }
    // stage x (cols 0..127)
    for (int i = t; i < TR * (H / 4); i += 512) {
        const int r = i / (H / 4), j4 = (i % (H / 4)) * 4;
        const uint2 v = *(const uint2*)&xin[(size_t)(row0 + r) * H + j4];
        const int byte = r * ROWB + ((j4 * 2) ^ ((r & 7) << 4));
        *(uint2*)(Xls + byte) = v;
    }
    // stage h (cols 128..255)
    for (int i = t; i < TR * (H / 4); i += 512) {
        const int r = i / (H / 4), j4 = (i % (H / 4)) * 4;
        const uint2 v = *(const uint2*)&h[(size_t)(row0 + r) * H + j4];
        const int byte = r * ROWB + ((H * 2 + j4 * 2) ^ ((r & 7) << 4));
        *(uint2*)(Xls + byte) = v;
    }
    __syncthreads();

    const int col = wv * 16 + lane15;
    const float bi = bias[0 * H + col];
    const float bf = bias[1 * H + col];
    const float bg = bias[2 * H + col];
    const float bo = bias[3 * H + col];
    const float wout = out_w[col];

    #pragma unroll
    for (int rt = 0; rt < TR / 16; ++rt) {
        const int arow = rt * 16 + lane15;
        const char* abase = Xls + arow * ROWB;
        f16x8 afrag[KSTEPS];
        #pragma unroll
        for (int ks = 0; ks < KSTEPS; ++ks) {
            const int byte = (ks * 64 + kgrp * 16) ^ ((arow & 7) << 4);
            afrag[ks] = ld_frag16(abase + byte);
        }
        f32x4 acc[4];
        #pragma unroll
        for (int q = 0; q < 4; ++q)
            #pragma unroll
            for (int r = 0; r < 4; ++r) acc[q][r] = 0.f;
        #pragma unroll
        for (int ks = 0; ks < KSTEPS; ++ks)
            #pragma unroll
            for (int q = 0; q < 4; ++q)
                acc[q] = __builtin_amdgcn_mfma_f32_16x16x32_f16(
                    afrag[ks], bfrag[q][ks], acc[q], 0, 0, 0);
        #pragma unroll
        for (int reg = 0; reg < 4; ++reg) {
            const int rl = rt * 16 + (l >> 4) * 4 + reg;
            const int grow = row0 + rl;
            const size_t off = (size_t)grow * H + col;
            const float ig = fsigmoid(acc[0][reg] + bi);
            const float fg = fsigmoid(acc[1][reg] + bf);
            const float gg = ftanh(acc[2][reg] + bg);
            const float og = fsigmoid(acc[3][reg] + bo);
            const float cold = cls[rl * 132 + col];
            const float c2 = fmaf(fg, cold, ig * gg);
            const float h2 = og * ftanh(c2);
            c[off] = c2;
            h[off] = (f16)h2;
            // fused output projection partial
            float pv = h2 * wout;
            pv += __shfl_xor(pv, 1);
            pv += __shfl_xor(pv, 2);
            pv += __shfl_xor(pv, 4);
            pv += __shfl_xor(pv, 8);
            if (lane15 == 0) out_part[rl][wv] = pv;
        }
    }
    __syncthreads();
    if (t < TR) {
        float s = out_part[t][0];
        #pragma unroll
        for (int w = 1; w < 8; ++w) s += out_part[t][w];
        outp[row0 + t] = s + out_b[0];
    }
}

// ---------------- CSR build (once; inc is step-invariant) ----------------
__global__ __launch_bounds__(256) void count_kernel(
    const int* __restrict__ inc, int* __restrict__ cnt)
{
    const int slot = blockIdx.x * 256 + threadIdx.x;
    atomicAdd(&cnt[inc[slot]], 1);
}

__global__ __launch_bounds__(1024) void scan_kernel(
    const int* __restrict__ cnt, int* __restrict__ ptr)
{
    __shared__ int sums[1024];
    const int t = threadIdx.x;
    const int base = t * 32;
    int local[32];
    int s = 0;
    #pragma unroll
    for (int i = 0; i < 32; ++i) { local[i] = s; s += cnt[base + i]; }
    sums[t] = s;
    __syncthreads();
    for (int off = 1; off < 1024; off <<= 1) {
        int v = 0;
        if (t >= off) v = sums[t - off];
        __syncthreads();
        sums[t] += v;
        __syncthreads();
    }
    const int excl = sums[t] - s;
    #pragma unroll
    for (int i = 0; i < 32; ++i) ptr[base + i] = excl + local[i];
    if (t == 1023) ptr[NN] = sums[1023];
}

__global__ __launch_bounds__(256) void fill_kernel(
    const int* __restrict__ inc, const int* __restrict__ ptr,
    int* __restrict__ cur, int* __restrict__ rowidx)
{
    const int slot = blockIdx.x * 256 + threadIdx.x;
    const int n = inc[slot];
    const int pos = atomicAdd(&cur[n], 1);
    rowidx[ptr[n] + pos] = slot >> 1;
}

// ---------------- weight transpose+convert (once) ----------------
__global__ __launch_bounds__(256) void transpose_w_kernel(
    const float* __restrict__ Wih, const float* __restrict__ Whh,
    f16* __restrict__ dst, int Hk, int K, int fourH)
{
    const int tid = blockIdx.x * 256 + threadIdx.x;
    if (tid >= K * fourH) return;
    const int col = tid / K, k = tid % K;
    const float v = (k < Hk) ? Wih[(size_t)k * fourH + col]
                             : Whh[(size_t)(k - Hk) * fourH + col];
    dst[tid] = (f16)v;
}

__global__ __launch_bounds__(256) void cvt_kernel(
    const float* __restrict__ src, f16* __restrict__ dst, int n2)
{
    const int i = blockIdx.x * 256 + threadIdx.x;
    if (i >= n2) return;
    const float2 v = ((const float2*)src)[i];
    ((unsigned int*)dst)[i] = pk2(v.x, v.y);
}

extern "C" void kernel_launch(void* const* d_in, const int* in_sizes, int n_in,
                              void* d_out, int out_size, void* d_ws, size_t ws_size,
                              hipStream_t stream) {
    const float* data_nodes = (const float*)d_in[0];
    const float* data_tE    = (const float*)d_in[1];
    const float* data_sE    = (const float*)d_in[2];
    const float* h_n0 = (const float*)d_in[3];
    const float* c_n0 = (const float*)d_in[4];
    const float* h_t0 = (const float*)d_in[5];
    const float* c_t0 = (const float*)d_in[6];
    const float* h_s0 = (const float*)d_in[7];
    const float* c_s0 = (const float*)d_in[8];
    const int*   inc  = (const int*)d_in[9];
    const float* t_enc_w = (const float*)d_in[10];
    const float* t_enc_b = (const float*)d_in[11];
    const float* t_Wih   = (const float*)d_in[12];
    const float* t_Whh   = (const float*)d_in[13];
    const float* t_b     = (const float*)d_in[14];
    const float* s_enc_w = (const float*)d_in[15];
    const float* s_enc_b = (const float*)d_in[16];
    const float* s_Wih   = (const float*)d_in[17];
    const float* s_Whh   = (const float*)d_in[18];
    const float* s_b     = (const float*)d_in[19];
    const float* n_enc_w = (const float*)d_in[20];
    const float* n_enc_b = (const float*)d_in[21];
    const float* ee_w    = (const float*)d_in[22];
    const float* ee_b    = (const float*)d_in[23];
    const float* n_Wih   = (const float*)d_in[24];
    const float* n_Whh   = (const float*)d_in[25];
    const float* n_b     = (const float*)d_in[26];
    const float* out_w   = (const float*)d_in[27];
    const float* out_b   = (const float*)d_in[28];
    float* out = (float*)d_out;

    // ---- workspace layout ----
    char* p = (char*)d_ws;
    f16*  ht16    = (f16*)p;  p += (size_t)NN * 64 * 2;
    f16*  hs16    = (f16*)p;  p += (size_t)EE * 64 * 2;
    f16*  hn16    = (f16*)p;  p += (size_t)NN * 128 * 2;
    f16*  xnode16 = (f16*)p;  p += (size_t)NN * 128 * 2;
    float* ct     = (float*)p; p += (size_t)NN * 64 * 4;
    float* cs     = (float*)p; p += (size_t)EE * 64 * 4;
    float* cn     = (float*)p; p += (size_t)NN * 128 * 4;
    f16*  Wt_t    = (f16*)p;  p += (size_t)256 * 128 * 2;
    f16*  Wt_s    = (f16*)p;  p += (size_t)256 * 128 * 2;
    f16*  Wt_n    = (f16*)p;  p += (size_t)512 * 256 * 2;
    f16*  Wt_ee   = (f16*)p;  p += (size_t)64 * 128 * 2;
    int*  csr_ptr = (int*)p;  p += (size_t)(NN + 8) * 4;
    int*  csr_row = (int*)p;  p += (size_t)2 * EE * 4;
    int*  cnt     = (int*)p;  p += (size_t)NN * 4;
    int*  cur     = (int*)p;  p += (size_t)NN * 4;

    // ---- one-time: state init, weight conversion, CSR ----
    cvt_kernel<<<(NN * 64 / 2 + 255) / 256, 256, 0, stream>>>(h_t0, ht16, NN * 64 / 2);
    cvt_kernel<<<(EE * 64 / 2 + 255) / 256, 256, 0, stream>>>(h_s0, hs16, EE * 64 / 2);
    cvt_kernel<<<(NN * 128 / 2 + 255) / 256, 256, 0, stream>>>(h_n0, hn16, NN * 128 / 2);
    hipMemcpyAsync(ct, c_t0, (size_t)NN * 64 * 4, hipMemcpyDeviceToDevice, stream);
    hipMemcpyAsync(cs, c_s0, (size_t)EE * 64 * 4, hipMemcpyDeviceToDevice, stream);
    hipMemcpyAsync(cn, c_n0, (size_t)NN * 128 * 4, hipMemcpyDeviceToDevice, stream);

    transpose_w_kernel<<<(256 * 128 + 255) / 256, 256, 0, stream>>>(t_Wih, t_Whh, Wt_t, 64, 128, 256);
    transpose_w_kernel<<<(256 * 128 + 255) / 256, 256, 0, stream>>>(s_Wih, s_Whh, Wt_s, 64, 128, 256);
    transpose_w_kernel<<<(512 * 256 + 255) / 256, 256, 0, stream>>>(n_Wih, n_Whh, Wt_n, 128, 256, 512);
    transpose_w_kernel<<<(64 * 128 + 255) / 256, 256, 0, stream>>>(ee_w, ee_w, Wt_ee, 128, 128, 64);

    hipMemsetAsync(cnt, 0, NN * sizeof(int), stream);
    hipMemsetAsync(cur, 0, NN * sizeof(int), stream);
    count_kernel<<<(2 * EE) / 256, 256, 0, stream>>>(inc, cnt);
    scan_kernel<<<1, 1024, 0, stream>>>(cnt, csr_ptr);
    fill_kernel<<<(2 * EE) / 256, 256, 0, stream>>>(inc, csr_ptr, cur, csr_row);

    const int edgeGrid = NN / 64 + EE / 64;   // 512 + 2048

    for (int st = 0; st < S_LEN; ++st) {
        const float* xt = data_tE + (size_t)st * NN * 2;
        const float* xs = data_sE + (size_t)st * EE * 2;
        const float* xn = data_nodes + (size_t)st * NN;

        edge_lstm_fused<<<edgeGrid, 256, 0, stream>>>(
            xt, xs, t_enc_w, t_enc_b, s_enc_w, s_enc_b,
            Wt_t, Wt_s, t_b, s_b, ht16, ct, hs16, cs);
        gather_embed<<<NN / 64, 256, 0, stream>>>(
            xn, ht16, hs16, csr_ptr, csr_row,
            n_enc_w, n_enc_b, Wt_ee, ee_b, xnode16);
        node_lstm<<<NN / 32, 512, 0, stream>>>(
            xnode16, Wt_n, n_b, out_w, out_b, hn16, cn,
            out + (size_t)st * NN);
    }
}

// Round 8
// 1706.954 us; speedup vs baseline: 1.1380x; 1.1380x over previous
//
#include <hip/hip_runtime.h>
#include <math.h>

// SRNN: S=16 steps, N=32768 nodes, E=131072 spatial edges.
// f16 MFMA gate GEMMs, B-resident weights. Numerics hardening:
//  - CSR edge lists sorted ascending (deterministic + matches segment_sum order)
//  - agg enters embed as hi/lo f16 pair (K=192) -> kills the f16-agg rounding
// Edge TR=64 fused T+S; node TR=128 with fused output projection; 2-deep
// register c-prefetch. h f16, c fp32.

#define S_LEN 16
#define NN 32768
#define EE 131072

typedef _Float16 f16;
typedef _Float16 f16x8 __attribute__((ext_vector_type(8)));
typedef float f32x4 __attribute__((ext_vector_type(4)));

__device__ __forceinline__ float fsigmoid(float x) {
    return __builtin_amdgcn_rcpf(1.0f + __builtin_amdgcn_exp2f(-1.44269504f * x));
}
__device__ __forceinline__ float ftanh(float x) {
    const float e = __builtin_amdgcn_exp2f(2.88539008f * x);
    return 1.0f - 2.0f * __builtin_amdgcn_rcpf(e + 1.0f);
}

__device__ __forceinline__ unsigned int pk2(float a, float b) {
    union { f16 h[2]; unsigned int u; } x;
    x.h[0] = (f16)a; x.h[1] = (f16)b;
    return x.u;
}

__device__ __forceinline__ f16x8 ld_frag16(const void* p) {
    union { uint4 v; f16x8 f; } x;
    x.v = *(const uint4*)p;
    return x.f;
}

// ---------------- fused edge LSTM (temporal + spatial), H=64 ----------------
// TR=64 rows/block, 4 waves. Wave wv owns hidden cols [16wv,16wv+16) for all
// 4 gates; B-fragments resident in VGPRs. c: 2-deep register prefetch.
__global__ __launch_bounds__(256) void edge_lstm_fused(
    const float* __restrict__ xT, const float* __restrict__ xS,
    const float* __restrict__ t_enc_w, const float* __restrict__ t_enc_b,
    const float* __restrict__ s_enc_w, const float* __restrict__ s_enc_b,
    const f16* __restrict__ WtT, const f16* __restrict__ WtS,
    const float* __restrict__ biasT, const float* __restrict__ biasS,
    f16* __restrict__ hT, float* __restrict__ cT,
    f16* __restrict__ hS, float* __restrict__ cS)
{
    constexpr int H = 64, K = 128, KSTEPS = 4, ROWB = 256, TR = 64;
    constexpr int RTN = TR / 16;   // 4
    __shared__ __align__(16) char Xls[TR * ROWB];   // 16 KB

    const int bT = NN / TR;   // 512
    const bool isT = (int)blockIdx.x < bT;
    const int row0 = (isT ? blockIdx.x : blockIdx.x - bT) * TR;
    const float* xf    = isT ? xT : xS;
    const float* enc_w = isT ? t_enc_w : s_enc_w;
    const float* enc_b = isT ? t_enc_b : s_enc_b;
    const f16*   Wt    = isT ? WtT : WtS;
    const float* bias  = isT ? biasT : biasS;
    f16*   h = isT ? hT : hS;
    float* c = isT ? cT : cS;

    const int t = threadIdx.x;
    const int wv = t >> 6, l = t & 63;
    const int lane15 = l & 15, kgrp = l >> 4;
    const int col = wv * 16 + lane15;

    // B fragments: resident in VGPRs
    f16x8 bfrag[4][KSTEPS];
    #pragma unroll
    for (int q = 0; q < 4; ++q) {
        const int colq = q * H + col;
        const f16* bp = Wt + (size_t)colq * K + kgrp * 8;
        #pragma unroll
        for (int ks = 0; ks < KSTEPS; ++ks)
            bfrag[q][ks] = ld_frag16(bp + ks * 32);
    }

    // stage x-enc (cols 0..63)
    for (int i = t; i < TR * (H / 2); i += 256) {
        const int r = i / (H / 2), j2 = (i % (H / 2)) * 2;
        const int grow = row0 + r;
        const float x0 = xf[grow * 2 + 0];
        const float x1 = xf[grow * 2 + 1];
        const float e0 = fmaxf(0.f, fmaf(x0, enc_w[j2],     fmaf(x1, enc_w[H + j2],     enc_b[j2])));
        const float e1 = fmaxf(0.f, fmaf(x0, enc_w[j2 + 1], fmaf(x1, enc_w[H + j2 + 1], enc_b[j2 + 1])));
        const int byte = r * ROWB + ((j2 * 2) ^ ((r & 7) << 4));
        *(unsigned int*)(Xls + byte) = pk2(e0, e1);
    }
    // stage h (cols 64..127)
    for (int i = t; i < TR * (H / 4); i += 256) {
        const int r = i / (H / 4), j4 = (i % (H / 4)) * 4;
        const uint2 v = *(const uint2*)&h[(size_t)(row0 + r) * H + j4];
        const int byte = r * ROWB + ((H * 2 + j4 * 2) ^ ((r & 7) << 4));
        *(uint2*)(Xls + byte) = v;
    }
    __syncthreads();

    const float bi = bias[0 * H + col];
    const float bf = bias[1 * H + col];
    const float bg = bias[2 * H + col];
    const float bo = bias[3 * H + col];

    float cprA[4], cprB[4];
    #pragma unroll
    for (int reg = 0; reg < 4; ++reg)
        cprA[reg] = c[(size_t)(row0 + kgrp * 4 + reg) * H + col];

    #pragma unroll
    for (int rt = 0; rt < RTN; ++rt) {
        if (rt + 1 < RTN) {
            #pragma unroll
            for (int reg = 0; reg < 4; ++reg)
                cprB[reg] = c[(size_t)(row0 + (rt + 1) * 16 + kgrp * 4 + reg) * H + col];
        }
        const int arow = rt * 16 + lane15;
        const char* abase = Xls + arow * ROWB;
        f16x8 afrag[KSTEPS];
        #pragma unroll
        for (int ks = 0; ks < KSTEPS; ++ks) {
            const int byte = (ks * 64 + kgrp * 16) ^ ((arow & 7) << 4);
            afrag[ks] = ld_frag16(abase + byte);
        }
        f32x4 acc[4];
        #pragma unroll
        for (int q = 0; q < 4; ++q)
            #pragma unroll
            for (int r = 0; r < 4; ++r) acc[q][r] = 0.f;
        #pragma unroll
        for (int ks = 0; ks < KSTEPS; ++ks)
            #pragma unroll
            for (int q = 0; q < 4; ++q)
                acc[q] = __builtin_amdgcn_mfma_f32_16x16x32_f16(
                    afrag[ks], bfrag[q][ks], acc[q], 0, 0, 0);
        #pragma unroll
        for (int reg = 0; reg < 4; ++reg) {
            const int rl = rt * 16 + kgrp * 4 + reg;
            const int grow = row0 + rl;
            const size_t off = (size_t)grow * H + col;
            const float ig = fsigmoid(acc[0][reg] + bi);
            const float fg = fsigmoid(acc[1][reg] + bf);
            const float gg = ftanh(acc[2][reg] + bg);
            const float og = fsigmoid(acc[3][reg] + bo);
            const float c2 = fmaf(fg, cprA[reg], ig * gg);
            c[off] = c2;
            h[off] = (f16)(og * ftanh(c2));
        }
        #pragma unroll
        for (int reg = 0; reg < 4; ++reg) cprA[reg] = cprB[reg];
    }
}

// ---------------- gather + embed fused (K=192: ht | agg_hi | agg_lo) --------
__global__ __launch_bounds__(256) void gather_embed(
    const float* __restrict__ xn,
    const f16* __restrict__ ht, const f16* __restrict__ hs,
    const int* __restrict__ ptr, const int* __restrict__ rowidx,
    const float* __restrict__ n_enc_w, const float* __restrict__ n_enc_b,
    const f16* __restrict__ Wt_ee2,  // [64][192]
    const float* __restrict__ ee_b,
    f16* __restrict__ xnode)
{
    constexpr int TR = 64, K = 192, KSTEPS = 6, ROWB = 384;
    __shared__ __align__(16) char Xls[TR * ROWB];   // 24 KB
    const int row0 = blockIdx.x * TR;
    const int t = threadIdx.x;
    const int wv = t >> 6, l = t & 63;
    const int lane15 = l & 15, kgrp = l >> 4;

    const int col = wv * 16 + lane15;
    f16x8 bfrag[KSTEPS];
    {
        const f16* bp = Wt_ee2 + (size_t)col * K + kgrp * 8;
        #pragma unroll
        for (int ks = 0; ks < KSTEPS; ++ks) bfrag[ks] = ld_frag16(bp + ks * 32);
    }

    // stage ht -> K cols 0..63
    for (int i = t; i < TR * 16; i += 256) {
        const int r = i / 16, j4 = (i % 16) * 4;
        const uint2 v = *(const uint2*)&ht[(size_t)(row0 + r) * 64 + j4];
        const int byte = r * ROWB + ((j4 * 2) ^ ((r & 7) << 4));
        *(uint2*)(Xls + byte) = v;
    }

    // CSR gather -> K cols 64..127 (hi) and 128..191 (lo).
    // 4 threads per row, 16 f16 cols each; fp32 accumulate in ascending edge
    // order (rowidx sorted -> deterministic, matches segment_sum order).
    {
        const int r = t >> 2, q = t & 3;
        const int n = row0 + r;
        const int beg = ptr[n], end = ptr[n + 1];
        const unsigned int* hs32 = (const unsigned int*)hs;
        float acc[16];
        #pragma unroll
        for (int j = 0; j < 16; ++j) acc[j] = 0.f;
        for (int i = beg; i < end; ++i) {
            const int e = rowidx[i];
            const unsigned int* ep = hs32 + (size_t)e * 32 + q * 8;
            #pragma unroll
            for (int j = 0; j < 8; ++j) {
                union { unsigned int u; f16 h[2]; } v;
                v.u = ep[j];
                acc[2 * j]     += (float)v.h[0];
                acc[2 * j + 1] += (float)v.h[1];
            }
        }
        #pragma unroll
        for (int j = 0; j < 8; ++j) {
            const float a0 = acc[2 * j], a1 = acc[2 * j + 1];
            const f16 h0 = (f16)a0, h1 = (f16)a1;
            const f16 l0 = (f16)(a0 - (float)h0), l1 = (f16)(a1 - (float)h1);
            union { f16 h[2]; unsigned int u; } hi, lo;
            hi.h[0] = h0; hi.h[1] = h1;
            lo.h[0] = l0; lo.h[1] = l1;
            const int bhi = r * ROWB + ((128 + q * 32 + j * 4) ^ ((r & 7) << 4));
            const int blo = r * ROWB + ((256 + q * 32 + j * 4) ^ ((r & 7) << 4));
            *(unsigned int*)(Xls + bhi) = hi.u;
            *(unsigned int*)(Xls + blo) = lo.u;
        }
    }
    __syncthreads();

    const float bb = ee_b[col];
    #pragma unroll
    for (int rt = 0; rt < TR / 16; ++rt) {
        const int arow = rt * 16 + lane15;
        const char* abase = Xls + arow * ROWB;
        f16x8 afrag[KSTEPS];
        #pragma unroll
        for (int ks = 0; ks < KSTEPS; ++ks) {
            const int byte = (ks * 64 + kgrp * 16) ^ ((arow & 7) << 4);
            afrag[ks] = ld_frag16(abase + byte);
        }
        f32x4 acc;
        #pragma unroll
        for (int r = 0; r < 4; ++r) acc[r] = 0.f;
        #pragma unroll
        for (int ks = 0; ks < KSTEPS; ++ks)
            acc = __builtin_amdgcn_mfma_f32_16x16x32_f16(afrag[ks], bfrag[ks], acc, 0, 0, 0);
        #pragma unroll
        for (int reg = 0; reg < 4; ++reg) {
            const int grow = row0 + rt * 16 + kgrp * 4 + reg;
            xnode[(size_t)grow * 128 + 64 + col] = (f16)fmaxf(0.f, acc[reg] + bb);
        }
    }

    // encoder half: cols 0..63
    for (int i = t; i < TR * 32; i += 256) {
        const int r = i >> 5, j2 = (i & 31) * 2;
        const int grow = row0 + r;
        const float x = xn[grow];
        const float e0 = fmaxf(0.f, fmaf(x, n_enc_w[j2],     n_enc_b[j2]));
        const float e1 = fmaxf(0.f, fmaf(x, n_enc_w[j2 + 1], n_enc_b[j2 + 1]));
        *(unsigned int*)&xnode[(size_t)grow * 128 + j2] = pk2(e0, e1);
    }
}

// ---------------- node LSTM (H=128) + fused output projection ----------------
__global__ __launch_bounds__(512) void node_lstm(
    const f16* __restrict__ xin,
    const f16* __restrict__ Wt,     // [512][256]
    const float* __restrict__ bias, // [512]
    const float* __restrict__ out_w, const float* __restrict__ out_b,
    f16* __restrict__ h, float* __restrict__ c, float* __restrict__ outp)
{
    constexpr int H = 128, K = 256, KSTEPS = 8, ROWB = 512, TR = 128;
    constexpr int RTN = TR / 16;   // 8
    __shared__ __align__(16) char Xls[TR * ROWB];   // 64 KB
    __shared__ float out_part[TR][8];               // 4 KB

    const int row0 = blockIdx.x * TR;
    const int t = threadIdx.x;
    const int wv = t >> 6, l = t & 63;
    const int lane15 = l & 15, kgrp = l >> 4;
    const int col = wv * 16 + lane15;

    f16x8 bfrag[4][KSTEPS];
    #pragma unroll
    for (int q = 0; q < 4; ++q) {
        const int colq = q * H + col;
        const f16* bp = Wt + (size_t)colq * K + kgrp * 8;
        #pragma unroll
        for (int ks = 0; ks < KSTEPS; ++ks)
            bfrag[q][ks] = ld_frag16(bp + ks * 32);
    }

    for (int i = t; i < TR * (H / 4); i += 512) {
        const int r = i / (H / 4), j4 = (i % (H / 4)) * 4;
        const uint2 v = *(const uint2*)&xin[(size_t)(row0 + r) * H + j4];
        const int byte = r * ROWB + ((j4 * 2) ^ ((r & 7) << 4));
        *(uint2*)(Xls + byte) = v;
    }
    for (int i = t; i < TR * (H / 4); i += 512) {
        const int r = i / (H / 4), j4 = (i % (H / 4)) * 4;
        const uint2 v = *(const uint2*)&h[(size_t)(row0 + r) * H + j4];
        const int byte = r * ROWB + ((H * 2 + j4 * 2) ^ ((r & 7) << 4));
        *(uint2*)(Xls + byte) = v;
    }
    __syncthreads();

    const float bi = bias[0 * H + col];
    const float bf = bias[1 * H + col];
    const float bg = bias[2 * H + col];
    const float bo = bias[3 * H + col];
    const float wout = out_w[col];

    float cprA[4], cprB[4];
    #pragma unroll
    for (int reg = 0; reg < 4; ++reg)
        cprA[reg] = c[(size_t)(row0 + kgrp * 4 + reg) * H + col];

    #pragma unroll
    for (int rt = 0; rt < RTN; ++rt) {
        if (rt + 1 < RTN) {
            #pragma unroll
            for (int reg = 0; reg < 4; ++reg)
                cprB[reg] = c[(size_t)(row0 + (rt + 1) * 16 + kgrp * 4 + reg) * H + col];
        }
        const int arow = rt * 16 + lane15;
        const char* abase = Xls + arow * ROWB;
        f16x8 afrag[KSTEPS];
        #pragma unroll
        for (int ks = 0; ks < KSTEPS; ++ks) {
            const int byte = (ks * 64 + kgrp * 16) ^ ((arow & 7) << 4);
            afrag[ks] = ld_frag16(abase + byte);
        }
        f32x4 acc[4];
        #pragma unroll
        for (int q = 0; q < 4; ++q)
            #pragma unroll
            for (int r = 0; r < 4; ++r) acc[q][r] = 0.f;
        #pragma unroll
        for (int ks = 0; ks < KSTEPS; ++ks)
            #pragma unroll
            for (int q = 0; q < 4; ++q)
                acc[q] = __builtin_amdgcn_mfma_f32_16x16x32_f16(
                    afrag[ks], bfrag[q][ks], acc[q], 0, 0, 0);
        #pragma unroll
        for (int reg = 0; reg < 4; ++reg) {
            const int rl = rt * 16 + kgrp * 4 + reg;
            const int grow = row0 + rl;
            const size_t off = (size_t)grow * H + col;
            const float ig = fsigmoid(acc[0][reg] + bi);
            const float fg = fsigmoid(acc[1][reg] + bf);
            const float gg = ftanh(acc[2][reg] + bg);
            const float og = fsigmoid(acc[3][reg] + bo);
            const float c2 = fmaf(fg, cprA[reg], ig * gg);
            const float h2 = og * ftanh(c2);
            c[off] = c2;
            h[off] = (f16)h2;
            float pv = h2 * wout;
            pv += __shfl_xor(pv, 1);
            pv += __shfl_xor(pv, 2);
            pv += __shfl_xor(pv, 4);
            pv += __shfl_xor(pv, 8);
            if (lane15 == 0) out_part[rl][wv] = pv;
        }
        #pragma unroll
        for (int reg = 0; reg < 4; ++reg) cprA[reg] = cprB[reg];
    }
    __syncthreads();
    if (t < TR) {
        float s = out_part[t][0];
        #pragma unroll
        for (int w = 1; w < 8; ++w) s += out_part[t][w];
        outp[row0 + t] = s + out_b[0];
    }
}

// ---------------- CSR build (once; inc is step-invariant) ----------------
__global__ __launch_bounds__(256) void count_kernel(
    const int* __restrict__ inc, int* __restrict__ cnt)
{
    const int slot = blockIdx.x * 256 + threadIdx.x;
    atomicAdd(&cnt[inc[slot]], 1);
}

__global__ __launch_bounds__(1024) void scan_kernel(
    const int* __restrict__ cnt, int* __restrict__ ptr)
{
    __shared__ int sums[1024];
    const int t = threadIdx.x;
    const int base = t * 32;
    int local[32];
    int s = 0;
    #pragma unroll
    for (int i = 0; i < 32; ++i) { local[i] = s; s += cnt[base + i]; }
    sums[t] = s;
    __syncthreads();
    for (int off = 1; off < 1024; off <<= 1) {
        int v = 0;
        if (t >= off) v = sums[t - off];
        __syncthreads();
        sums[t] += v;
        __syncthreads();
    }
    const int excl = sums[t] - s;
    #pragma unroll
    for (int i = 0; i < 32; ++i) ptr[base + i] = excl + local[i];
    if (t == 1023) ptr[NN] = sums[1023];
}

__global__ __launch_bounds__(256) void fill_kernel(
    const int* __restrict__ inc, const int* __restrict__ ptr,
    int* __restrict__ cur, int* __restrict__ rowidx)
{
    const int slot = blockIdx.x * 256 + threadIdx.x;
    const int n = inc[slot];
    const int pos = atomicAdd(&cur[n], 1);
    rowidx[ptr[n] + pos] = slot >> 1;
}

// Sort each node's edge list ascending (deterministic; matches segment_sum
// accumulation order). One thread per node, selection sort (deg ~ 8).
__global__ __launch_bounds__(256) void sort_csr_kernel(
    const int* __restrict__ ptr, int* __restrict__ rowidx)
{
    const int n = blockIdx.x * 256 + threadIdx.x;
    if (n >= NN) return;
    const int beg = ptr[n], end = ptr[n + 1];
    for (int i = beg; i < end - 1; ++i) {
        int mi = i, mv = rowidx[i];
        for (int j = i + 1; j < end; ++j) {
            const int v = rowidx[j];
            if (v < mv) { mv = v; mi = j; }
        }
        if (mi != i) { rowidx[mi] = rowidx[i]; rowidx[i] = mv; }
    }
}

// ---------------- weight transpose+convert (once) ----------------
__global__ __launch_bounds__(256) void transpose_w_kernel(
    const float* __restrict__ Wih, const float* __restrict__ Whh,
    f16* __restrict__ dst, int Hk, int K, int fourH)
{
    const int tid = blockIdx.x * 256 + threadIdx.x;
    if (tid >= K * fourH) return;
    const int col = tid / K, k = tid % K;
    const float v = (k < Hk) ? Wih[(size_t)k * fourH + col]
                             : Whh[(size_t)(k - Hk) * fourH + col];
    dst[tid] = (f16)v;
}

// ee_w (128,64) -> Wt_ee2 [64][192]: k<128 -> row k; k>=128 -> row k-64
// (agg rows 64..127 duplicated for the lo half).
__global__ __launch_bounds__(256) void transpose_ee2_kernel(
    const float* __restrict__ ee_w, f16* __restrict__ dst)
{
    const int tid = blockIdx.x * 256 + threadIdx.x;
    if (tid >= 64 * 192) return;
    const int col = tid / 192, k = tid % 192;
    const int srcrow = (k < 128) ? k : (k - 64);
    dst[tid] = (f16)ee_w[(size_t)srcrow * 64 + col];
}

__global__ __launch_bounds__(256) void cvt_kernel(
    const float* __restrict__ src, f16* __restrict__ dst, int n2)
{
    const int i = blockIdx.x * 256 + threadIdx.x;
    if (i >= n2) return;
    const float2 v = ((const float2*)src)[i];
    ((unsigned int*)dst)[i] = pk2(v.x, v.y);
}

extern "C" void kernel_launch(void* const* d_in, const int* in_sizes, int n_in,
                              void* d_out, int out_size, void* d_ws, size_t ws_size,
                              hipStream_t stream) {
    const float* data_nodes = (const float*)d_in[0];
    const float* data_tE    = (const float*)d_in[1];
    const float* data_sE    = (const float*)d_in[2];
    const float* h_n0 = (const float*)d_in[3];
    const float* c_n0 = (const float*)d_in[4];
    const float* h_t0 = (const float*)d_in[5];
    const float* c_t0 = (const float*)d_in[6];
    const float* h_s0 = (const float*)d_in[7];
    const float* c_s0 = (const float*)d_in[8];
    const int*   inc  = (const int*)d_in[9];
    const float* t_enc_w = (const float*)d_in[10];
    const float* t_enc_b = (const float*)d_in[11];
    const float* t_Wih   = (const float*)d_in[12];
    const float* t_Whh   = (const float*)d_in[13];
    const float* t_b     = (const float*)d_in[14];
    const float* s_enc_w = (const float*)d_in[15];
    const float* s_enc_b = (const float*)d_in[16];
    const float* s_Wih   = (const float*)d_in[17];
    const float* s_Whh   = (const float*)d_in[18];
    const float* s_b     = (const float*)d_in[19];
    const float* n_enc_w = (const float*)d_in[20];
    const float* n_enc_b = (const float*)d_in[21];
    const float* ee_w    = (const float*)d_in[22];
    const float* ee_b    = (const float*)d_in[23];
    const float* n_Wih   = (const float*)d_in[24];
    const float* n_Whh   = (const float*)d_in[25];
    const float* n_b     = (const float*)d_in[26];
    const float* out_w   = (const float*)d_in[27];
    const float* out_b   = (const float*)d_in[28];
    float* out = (float*)d_out;

    // ---- workspace layout ----
    char* p = (char*)d_ws;
    f16*  ht16    = (f16*)p;  p += (size_t)NN * 64 * 2;
    f16*  hs16    = (f16*)p;  p += (size_t)EE * 64 * 2;
    f16*  hn16    = (f16*)p;  p += (size_t)NN * 128 * 2;
    f16*  xnode16 = (f16*)p;  p += (size_t)NN * 128 * 2;
    float* ct     = (float*)p; p += (size_t)NN * 64 * 4;
    float* cs     = (float*)p; p += (size_t)EE * 64 * 4;
    float* cn     = (float*)p; p += (size_t)NN * 128 * 4;
    f16*  Wt_t    = (f16*)p;  p += (size_t)256 * 128 * 2;
    f16*  Wt_s    = (f16*)p;  p += (size_t)256 * 128 * 2;
    f16*  Wt_n    = (f16*)p;  p += (size_t)512 * 256 * 2;
    f16*  Wt_ee2  = (f16*)p;  p += (size_t)64 * 192 * 2;
    int*  csr_ptr = (int*)p;  p += (size_t)(NN + 8) * 4;
    int*  csr_row = (int*)p;  p += (size_t)2 * EE * 4;
    int*  cnt     = (int*)p;  p += (size_t)NN * 4;
    int*  cur     = (int*)p;  p += (size_t)NN * 4;

    // ---- one-time: state init, weight conversion, CSR ----
    cvt_kernel<<<(NN * 64 / 2 + 255) / 256, 256, 0, stream>>>(h_t0, ht16, NN * 64 / 2);
    cvt_kernel<<<(EE * 64 / 2 + 255) / 256, 256, 0, stream>>>(h_s0, hs16, EE * 64 / 2);
    cvt_kernel<<<(NN * 128 / 2 + 255) / 256, 256, 0, stream>>>(h_n0, hn16, NN * 128 / 2);
    hipMemcpyAsync(ct, c_t0, (size_t)NN * 64 * 4, hipMemcpyDeviceToDevice, stream);
    hipMemcpyAsync(cs, c_s0, (size_t)EE * 64 * 4, hipMemcpyDeviceToDevice, stream);
    hipMemcpyAsync(cn, c_n0, (size_t)NN * 128 * 4, hipMemcpyDeviceToDevice, stream);

    transpose_w_kernel<<<(256 * 128 + 255) / 256, 256, 0, stream>>>(t_Wih, t_Whh, Wt_t, 64, 128, 256);
    transpose_w_kernel<<<(256 * 128 + 255) / 256, 256, 0, stream>>>(s_Wih, s_Whh, Wt_s, 64, 128, 256);
    transpose_w_kernel<<<(512 * 256 + 255) / 256, 256, 0, stream>>>(n_Wih, n_Whh, Wt_n, 128, 256, 512);
    transpose_ee2_kernel<<<(64 * 192 + 255) / 256, 256, 0, stream>>>(ee_w, Wt_ee2);

    hipMemsetAsync(cnt, 0, NN * sizeof(int), stream);
    hipMemsetAsync(cur, 0, NN * sizeof(int), stream);
    count_kernel<<<(2 * EE) / 256, 256, 0, stream>>>(inc, cnt);
    scan_kernel<<<1, 1024, 0, stream>>>(cnt, csr_ptr);
    fill_kernel<<<(2 * EE) / 256, 256, 0, stream>>>(inc, csr_ptr, cur, csr_row);
    sort_csr_kernel<<<NN / 256, 256, 0, stream>>>(csr_ptr, csr_row);

    const int edgeGrid = NN / 64 + EE / 64;   // 512 + 2048 = 2560

    for (int st = 0; st < S_LEN; ++st) {
        const float* xt = data_tE + (size_t)st * NN * 2;
        const float* xs = data_sE + (size_t)st * EE * 2;
        const float* xn = data_nodes + (size_t)st * NN;

        edge_lstm_fused<<<edgeGrid, 256, 0, stream>>>(
            xt, xs, t_enc_w, t_enc_b, s_enc_w, s_enc_b,
            Wt_t, Wt_s, t_b, s_b, ht16, ct, hs16, cs);
        gather_embed<<<NN / 64, 256, 0, stream>>>(
            xn, ht16, hs16, csr_ptr, csr_row,
            n_enc_w, n_enc_b, Wt_ee2, ee_b, xnode16);
        node_lstm<<<NN / 128, 512, 0, stream>>>(
            xnode16, Wt_n, n_b, out_w, out_b, hn16, cn,
            out + (size_t)st * NN);
    }
}

// Round 9
// 1645.882 us; speedup vs baseline: 1.1802x; 1.0371x over previous
//
#include <hip/hip_runtime.h>
#include <math.h>

// SRNN: S=16 steps, N=32768 nodes, E=131072 spatial edges.
// f16 MFMA gate GEMMs, B-resident weights. Numerics hardening (kept):
//  - CSR edge lists sorted ascending (deterministic, matches segment_sum order)
//  - agg enters embed as hi/lo f16 pair (K=192)
// Geometry: edge fused T+S TR=128 (8 rt iters amortize B-load+staging),
// node TR=128 + fused output projection. NO c-prefetch (r8 showed it costs
// occupancy: VGPR 64->88, occ 33->19 -> slower). h f16, c fp32.

#define S_LEN 16
#define NN 32768
#define EE 131072

typedef _Float16 f16;
typedef _Float16 f16x8 __attribute__((ext_vector_type(8)));
typedef float f32x4 __attribute__((ext_vector_type(4)));

__device__ __forceinline__ float fsigmoid(float x) {
    return __builtin_amdgcn_rcpf(1.0f + __builtin_amdgcn_exp2f(-1.44269504f * x));
}
__device__ __forceinline__ float ftanh(float x) {
    const float e = __builtin_amdgcn_exp2f(2.88539008f * x);
    return 1.0f - 2.0f * __builtin_amdgcn_rcpf(e + 1.0f);
}

__device__ __forceinline__ unsigned int pk2(float a, float b) {
    union { f16 h[2]; unsigned int u; } x;
    x.h[0] = (f16)a; x.h[1] = (f16)b;
    return x.u;
}

__device__ __forceinline__ f16x8 ld_frag16(const void* p) {
    union { uint4 v; f16x8 f; } x;
    x.v = *(const uint4*)p;
    return x.f;
}

// ---------------- fused edge LSTM (temporal + spatial), H=64 ----------------
// TR=128 rows/block, 4 waves. Wave wv owns hidden cols [16wv,16wv+16) for all
// 4 gates across 8 row-tiles; B-fragments resident in VGPRs.
__global__ __launch_bounds__(256) void edge_lstm_fused(
    const float* __restrict__ xT, const float* __restrict__ xS,
    const float* __restrict__ t_enc_w, const float* __restrict__ t_enc_b,
    const float* __restrict__ s_enc_w, const float* __restrict__ s_enc_b,
    const f16* __restrict__ WtT, const f16* __restrict__ WtS,
    const float* __restrict__ biasT, const float* __restrict__ biasS,
    f16* __restrict__ hT, float* __restrict__ cT,
    f16* __restrict__ hS, float* __restrict__ cS)
{
    constexpr int H = 64, K = 128, KSTEPS = 4, ROWB = 256, TR = 128;
    constexpr int RTN = TR / 16;   // 8
    __shared__ __align__(16) char Xls[TR * ROWB];   // 32 KB

    const int bT = NN / TR;   // 256
    const bool isT = (int)blockIdx.x < bT;
    const int row0 = (isT ? blockIdx.x : blockIdx.x - bT) * TR;
    const float* xf    = isT ? xT : xS;
    const float* enc_w = isT ? t_enc_w : s_enc_w;
    const float* enc_b = isT ? t_enc_b : s_enc_b;
    const f16*   Wt    = isT ? WtT : WtS;
    const float* bias  = isT ? biasT : biasS;
    f16*   h = isT ? hT : hS;
    float* c = isT ? cT : cS;

    const int t = threadIdx.x;
    const int wv = t >> 6, l = t & 63;
    const int lane15 = l & 15, kgrp = l >> 4;
    const int col = wv * 16 + lane15;

    // B fragments: resident in VGPRs
    f16x8 bfrag[4][KSTEPS];
    #pragma unroll
    for (int q = 0; q < 4; ++q) {
        const int colq = q * H + col;
        const f16* bp = Wt + (size_t)colq * K + kgrp * 8;
        #pragma unroll
        for (int ks = 0; ks < KSTEPS; ++ks)
            bfrag[q][ks] = ld_frag16(bp + ks * 32);
    }

    // stage x-enc (cols 0..63)
    for (int i = t; i < TR * (H / 2); i += 256) {
        const int r = i / (H / 2), j2 = (i % (H / 2)) * 2;
        const int grow = row0 + r;
        const float x0 = xf[grow * 2 + 0];
        const float x1 = xf[grow * 2 + 1];
        const float e0 = fmaxf(0.f, fmaf(x0, enc_w[j2],     fmaf(x1, enc_w[H + j2],     enc_b[j2])));
        const float e1 = fmaxf(0.f, fmaf(x0, enc_w[j2 + 1], fmaf(x1, enc_w[H + j2 + 1], enc_b[j2 + 1])));
        const int byte = r * ROWB + ((j2 * 2) ^ ((r & 7) << 4));
        *(unsigned int*)(Xls + byte) = pk2(e0, e1);
    }
    // stage h (cols 64..127)
    for (int i = t; i < TR * (H / 4); i += 256) {
        const int r = i / (H / 4), j4 = (i % (H / 4)) * 4;
        const uint2 v = *(const uint2*)&h[(size_t)(row0 + r) * H + j4];
        const int byte = r * ROWB + ((H * 2 + j4 * 2) ^ ((r & 7) << 4));
        *(uint2*)(Xls + byte) = v;
    }
    __syncthreads();

    const float bi = bias[0 * H + col];
    const float bf = bias[1 * H + col];
    const float bg = bias[2 * H + col];
    const float bo = bias[3 * H + col];

    #pragma unroll
    for (int rt = 0; rt < RTN; ++rt) {
        const int arow = rt * 16 + lane15;
        const char* abase = Xls + arow * ROWB;
        f16x8 afrag[KSTEPS];
        #pragma unroll
        for (int ks = 0; ks < KSTEPS; ++ks) {
            const int byte = (ks * 64 + kgrp * 16) ^ ((arow & 7) << 4);
            afrag[ks] = ld_frag16(abase + byte);
        }
        f32x4 acc[4];
        #pragma unroll
        for (int q = 0; q < 4; ++q)
            #pragma unroll
            for (int r = 0; r < 4; ++r) acc[q][r] = 0.f;
        #pragma unroll
        for (int ks = 0; ks < KSTEPS; ++ks)
            #pragma unroll
            for (int q = 0; q < 4; ++q)
                acc[q] = __builtin_amdgcn_mfma_f32_16x16x32_f16(
                    afrag[ks], bfrag[q][ks], acc[q], 0, 0, 0);
        #pragma unroll
        for (int reg = 0; reg < 4; ++reg) {
            const int rl = rt * 16 + kgrp * 4 + reg;
            const int grow = row0 + rl;
            const size_t off = (size_t)grow * H + col;
            const float ig = fsigmoid(acc[0][reg] + bi);
            const float fg = fsigmoid(acc[1][reg] + bf);
            const float gg = ftanh(acc[2][reg] + bg);
            const float og = fsigmoid(acc[3][reg] + bo);
            const float c2 = fmaf(fg, c[off], ig * gg);
            c[off] = c2;
            h[off] = (f16)(og * ftanh(c2));
        }
    }
}

// ---------------- gather + embed fused (K=192: ht | agg_hi | agg_lo) --------
__global__ __launch_bounds__(256) void gather_embed(
    const float* __restrict__ xn,
    const f16* __restrict__ ht, const f16* __restrict__ hs,
    const int* __restrict__ ptr, const int* __restrict__ rowidx,
    const float* __restrict__ n_enc_w, const float* __restrict__ n_enc_b,
    const f16* __restrict__ Wt_ee2,  // [64][192]
    const float* __restrict__ ee_b,
    f16* __restrict__ xnode)
{
    constexpr int TR = 64, K = 192, KSTEPS = 6, ROWB = 384;
    __shared__ __align__(16) char Xls[TR * ROWB];   // 24 KB
    const int row0 = blockIdx.x * TR;
    const int t = threadIdx.x;
    const int wv = t >> 6, l = t & 63;
    const int lane15 = l & 15, kgrp = l >> 4;

    const int col = wv * 16 + lane15;
    f16x8 bfrag[KSTEPS];
    {
        const f16* bp = Wt_ee2 + (size_t)col * K + kgrp * 8;
        #pragma unroll
        for (int ks = 0; ks < KSTEPS; ++ks) bfrag[ks] = ld_frag16(bp + ks * 32);
    }

    // stage ht -> K cols 0..63
    for (int i = t; i < TR * 16; i += 256) {
        const int r = i / 16, j4 = (i % 16) * 4;
        const uint2 v = *(const uint2*)&ht[(size_t)(row0 + r) * 64 + j4];
        const int byte = r * ROWB + ((j4 * 2) ^ ((r & 7) << 4));
        *(uint2*)(Xls + byte) = v;
    }

    // CSR gather -> K cols 64..127 (hi) and 128..191 (lo), sorted edge order.
    {
        const int r = t >> 2, q = t & 3;
        const int n = row0 + r;
        const int beg = ptr[n], end = ptr[n + 1];
        const unsigned int* hs32 = (const unsigned int*)hs;
        float acc[16];
        #pragma unroll
        for (int j = 0; j < 16; ++j) acc[j] = 0.f;
        for (int i = beg; i < end; ++i) {
            const int e = rowidx[i];
            const unsigned int* ep = hs32 + (size_t)e * 32 + q * 8;
            #pragma unroll
            for (int j = 0; j < 8; ++j) {
                union { unsigned int u; f16 h[2]; } v;
                v.u = ep[j];
                acc[2 * j]     += (float)v.h[0];
                acc[2 * j + 1] += (float)v.h[1];
            }
        }
        #pragma unroll
        for (int j = 0; j < 8; ++j) {
            const float a0 = acc[2 * j], a1 = acc[2 * j + 1];
            const f16 h0 = (f16)a0, h1 = (f16)a1;
            const f16 l0 = (f16)(a0 - (float)h0), l1 = (f16)(a1 - (float)h1);
            union { f16 h[2]; unsigned int u; } hi, lo;
            hi.h[0] = h0; hi.h[1] = h1;
            lo.h[0] = l0; lo.h[1] = l1;
            const int bhi = r * ROWB + ((128 + q * 32 + j * 4) ^ ((r & 7) << 4));
            const int blo = r * ROWB + ((256 + q * 32 + j * 4) ^ ((r & 7) << 4));
            *(unsigned int*)(Xls + bhi) = hi.u;
            *(unsigned int*)(Xls + blo) = lo.u;
        }
    }
    __syncthreads();

    const float bb = ee_b[col];
    #pragma unroll
    for (int rt = 0; rt < TR / 16; ++rt) {
        const int arow = rt * 16 + lane15;
        const char* abase = Xls + arow * ROWB;
        f16x8 afrag[KSTEPS];
        #pragma unroll
        for (int ks = 0; ks < KSTEPS; ++ks) {
            const int byte = (ks * 64 + kgrp * 16) ^ ((arow & 7) << 4);
            afrag[ks] = ld_frag16(abase + byte);
        }
        f32x4 acc;
        #pragma unroll
        for (int r = 0; r < 4; ++r) acc[r] = 0.f;
        #pragma unroll
        for (int ks = 0; ks < KSTEPS; ++ks)
            acc = __builtin_amdgcn_mfma_f32_16x16x32_f16(afrag[ks], bfrag[ks], acc, 0, 0, 0);
        #pragma unroll
        for (int reg = 0; reg < 4; ++reg) {
            const int grow = row0 + rt * 16 + kgrp * 4 + reg;
            xnode[(size_t)grow * 128 + 64 + col] = (f16)fmaxf(0.f, acc[reg] + bb);
        }
    }

    // encoder half: cols 0..63
    for (int i = t; i < TR * 32; i += 256) {
        const int r = i >> 5, j2 = (i & 31) * 2;
        const int grow = row0 + r;
        const float x = xn[grow];
        const float e0 = fmaxf(0.f, fmaf(x, n_enc_w[j2],     n_enc_b[j2]));
        const float e1 = fmaxf(0.f, fmaf(x, n_enc_w[j2 + 1], n_enc_b[j2 + 1]));
        *(unsigned int*)&xnode[(size_t)grow * 128 + j2] = pk2(e0, e1);
    }
}

// ---------------- node LSTM (H=128) + fused output projection ----------------
__global__ __launch_bounds__(512) void node_lstm(
    const f16* __restrict__ xin,
    const f16* __restrict__ Wt,     // [512][256]
    const float* __restrict__ bias, // [512]
    const float* __restrict__ out_w, const float* __restrict__ out_b,
    f16* __restrict__ h, float* __restrict__ c, float* __restrict__ outp)
{
    constexpr int H = 128, K = 256, KSTEPS = 8, ROWB = 512, TR = 128;
    constexpr int RTN = TR / 16;   // 8
    __shared__ __align__(16) char Xls[TR * ROWB];   // 64 KB
    __shared__ float out_part[TR][8];               // 4 KB

    const int row0 = blockIdx.x * TR;
    const int t = threadIdx.x;
    const int wv = t >> 6, l = t & 63;
    const int lane15 = l & 15, kgrp = l >> 4;
    const int col = wv * 16 + lane15;

    f16x8 bfrag[4][KSTEPS];
    #pragma unroll
    for (int q = 0; q < 4; ++q) {
        const int colq = q * H + col;
        const f16* bp = Wt + (size_t)colq * K + kgrp * 8;
        #pragma unroll
        for (int ks = 0; ks < KSTEPS; ++ks)
            bfrag[q][ks] = ld_frag16(bp + ks * 32);
    }

    for (int i = t; i < TR * (H / 4); i += 512) {
        const int r = i / (H / 4), j4 = (i % (H / 4)) * 4;
        const uint2 v = *(const uint2*)&xin[(size_t)(row0 + r) * H + j4];
        const int byte = r * ROWB + ((j4 * 2) ^ ((r & 7) << 4));
        *(uint2*)(Xls + byte) = v;
    }
    for (int i = t; i < TR * (H / 4); i += 512) {
        const int r = i / (H / 4), j4 = (i % (H / 4)) * 4;
        const uint2 v = *(const uint2*)&h[(size_t)(row0 + r) * H + j4];
        const int byte = r * ROWB + ((H * 2 + j4 * 2) ^ ((r & 7) << 4));
        *(uint2*)(Xls + byte) = v;
    }
    __syncthreads();

    const float bi = bias[0 * H + col];
    const float bf = bias[1 * H + col];
    const float bg = bias[2 * H + col];
    const float bo = bias[3 * H + col];
    const float wout = out_w[col];

    #pragma unroll
    for (int rt = 0; rt < RTN; ++rt) {
        const int arow = rt * 16 + lane15;
        const char* abase = Xls + arow * ROWB;
        f16x8 afrag[KSTEPS];
        #pragma unroll
        for (int ks = 0; ks < KSTEPS; ++ks) {
            const int byte = (ks * 64 + kgrp * 16) ^ ((arow & 7) << 4);
            afrag[ks] = ld_frag16(abase + byte);
        }
        f32x4 acc[4];
        #pragma unroll
        for (int q = 0; q < 4; ++q)
            #pragma unroll
            for (int r = 0; r < 4; ++r) acc[q][r] = 0.f;
        #pragma unroll
        for (int ks = 0; ks < KSTEPS; ++ks)
            #pragma unroll
            for (int q = 0; q < 4; ++q)
                acc[q] = __builtin_amdgcn_mfma_f32_16x16x32_f16(
                    afrag[ks], bfrag[q][ks], acc[q], 0, 0, 0);
        #pragma unroll
        for (int reg = 0; reg < 4; ++reg) {
            const int rl = rt * 16 + kgrp * 4 + reg;
            const int grow = row0 + rl;
            const size_t off = (size_t)grow * H + col;
            const float ig = fsigmoid(acc[0][reg] + bi);
            const float fg = fsigmoid(acc[1][reg] + bf);
            const float gg = ftanh(acc[2][reg] + bg);
            const float og = fsigmoid(acc[3][reg] + bo);
            const float c2 = fmaf(fg, c[off], ig * gg);
            const float h2 = og * ftanh(c2);
            c[off] = c2;
            h[off] = (f16)h2;
            float pv = h2 * wout;
            pv += __shfl_xor(pv, 1);
            pv += __shfl_xor(pv, 2);
            pv += __shfl_xor(pv, 4);
            pv += __shfl_xor(pv, 8);
            if (lane15 == 0) out_part[rl][wv] = pv;
        }
    }
    __syncthreads();
    if (t < TR) {
        float s = out_part[t][0];
        #pragma unroll
        for (int w = 1; w < 8; ++w) s += out_part[t][w];
        outp[row0 + t] = s + out_b[0];
    }
}

// ---------------- CSR build (once; inc is step-invariant) ----------------
__global__ __launch_bounds__(256) void count_kernel(
    const int* __restrict__ inc, int* __restrict__ cnt)
{
    const int slot = blockIdx.x * 256 + threadIdx.x;
    atomicAdd(&cnt[inc[slot]], 1);
}

__global__ __launch_bounds__(1024) void scan_kernel(
    const int* __restrict__ cnt, int* __restrict__ ptr)
{
    __shared__ int sums[1024];
    const int t = threadIdx.x;
    const int base = t * 32;
    int local[32];
    int s = 0;
    #pragma unroll
    for (int i = 0; i < 32; ++i) { local[i] = s; s += cnt[base + i]; }
    sums[t] = s;
    __syncthreads();
    for (int off = 1; off < 1024; off <<= 1) {
        int v = 0;
        if (t >= off) v = sums[t - off];
        __syncthreads();
        sums[t] += v;
        __syncthreads();
    }
    const int excl = sums[t] - s;
    #pragma unroll
    for (int i = 0; i < 32; ++i) ptr[base + i] = excl + local[i];
    if (t == 1023) ptr[NN] = sums[1023];
}

__global__ __launch_bounds__(256) void fill_kernel(
    const int* __restrict__ inc, const int* __restrict__ ptr,
    int* __restrict__ cur, int* __restrict__ rowidx)
{
    const int slot = blockIdx.x * 256 + threadIdx.x;
    const int n = inc[slot];
    const int pos = atomicAdd(&cur[n], 1);
    rowidx[ptr[n] + pos] = slot >> 1;
}

// Sort each node's edge list ascending (deterministic; matches segment_sum
// accumulation order). One thread per node, selection sort (deg ~ 8).
__global__ __launch_bounds__(256) void sort_csr_kernel(
    const int* __restrict__ ptr, int* __restrict__ rowidx)
{
    const int n = blockIdx.x * 256 + threadIdx.x;
    if (n >= NN) return;
    const int beg = ptr[n], end = ptr[n + 1];
    for (int i = beg; i < end - 1; ++i) {
        int mi = i, mv = rowidx[i];
        for (int j = i + 1; j < end; ++j) {
            const int v = rowidx[j];
            if (v < mv) { mv = v; mi = j; }
        }
        if (mi != i) { rowidx[mi] = rowidx[i]; rowidx[i] = mv; }
    }
}

// ---------------- weight transpose+convert (once) ----------------
__global__ __launch_bounds__(256) void transpose_w_kernel(
    const float* __restrict__ Wih, const float* __restrict__ Whh,
    f16* __restrict__ dst, int Hk, int K, int fourH)
{
    const int tid = blockIdx.x * 256 + threadIdx.x;
    if (tid >= K * fourH) return;
    const int col = tid / K, k = tid % K;
    const float v = (k < Hk) ? Wih[(size_t)k * fourH + col]
                             : Whh[(size_t)(k - Hk) * fourH + col];
    dst[tid] = (f16)v;
}

// ee_w (128,64) -> Wt_ee2 [64][192]: k<128 -> row k; k>=128 -> row k-64.
__global__ __launch_bounds__(256) void transpose_ee2_kernel(
    const float* __restrict__ ee_w, f16* __restrict__ dst)
{
    const int tid = blockIdx.x * 256 + threadIdx.x;
    if (tid >= 64 * 192) return;
    const int col = tid / 192, k = tid % 192;
    const int srcrow = (k < 128) ? k : (k - 64);
    dst[tid] = (f16)ee_w[(size_t)srcrow * 64 + col];
}

__global__ __launch_bounds__(256) void cvt_kernel(
    const float* __restrict__ src, f16* __restrict__ dst, int n2)
{
    const int i = blockIdx.x * 256 + threadIdx.x;
    if (i >= n2) return;
    const float2 v = ((const float2*)src)[i];
    ((unsigned int*)dst)[i] = pk2(v.x, v.y);
}

extern "C" void kernel_launch(void* const* d_in, const int* in_sizes, int n_in,
                              void* d_out, int out_size, void* d_ws, size_t ws_size,
                              hipStream_t stream) {
    const float* data_nodes = (const float*)d_in[0];
    const float* data_tE    = (const float*)d_in[1];
    const float* data_sE    = (const float*)d_in[2];
    const float* h_n0 = (const float*)d_in[3];
    const float* c_n0 = (const float*)d_in[4];
    const float* h_t0 = (const float*)d_in[5];
    const float* c_t0 = (const float*)d_in[6];
    const float* h_s0 = (const float*)d_in[7];
    const float* c_s0 = (const float*)d_in[8];
    const int*   inc  = (const int*)d_in[9];
    const float* t_enc_w = (const float*)d_in[10];
    const float* t_enc_b = (const float*)d_in[11];
    const float* t_Wih   = (const float*)d_in[12];
    const float* t_Whh   = (const float*)d_in[13];
    const float* t_b     = (const float*)d_in[14];
    const float* s_enc_w = (const float*)d_in[15];
    const float* s_enc_b = (const float*)d_in[16];
    const float* s_Wih   = (const float*)d_in[17];
    const float* s_Whh   = (const float*)d_in[18];
    const float* s_b     = (const float*)d_in[19];
    const float* n_enc_w = (const float*)d_in[20];
    const float* n_enc_b = (const float*)d_in[21];
    const float* ee_w    = (const float*)d_in[22];
    const float* ee_b    = (const float*)d_in[23];
    const float* n_Wih   = (const float*)d_in[24];
    const float* n_Whh   = (const float*)d_in[25];
    const float* n_b     = (const float*)d_in[26];
    const float* out_w   = (const float*)d_in[27];
    const float* out_b   = (const float*)d_in[28];
    float* out = (float*)d_out;

    // ---- workspace layout ----
    char* p = (char*)d_ws;
    f16*  ht16    = (f16*)p;  p += (size_t)NN * 64 * 2;
    f16*  hs16    = (f16*)p;  p += (size_t)EE * 64 * 2;
    f16*  hn16    = (f16*)p;  p += (size_t)NN * 128 * 2;
    f16*  xnode16 = (f16*)p;  p += (size_t)NN * 128 * 2;
    float* ct     = (float*)p; p += (size_t)NN * 64 * 4;
    float* cs     = (float*)p; p += (size_t)EE * 64 * 4;
    float* cn     = (float*)p; p += (size_t)NN * 128 * 4;
    f16*  Wt_t    = (f16*)p;  p += (size_t)256 * 128 * 2;
    f16*  Wt_s    = (f16*)p;  p += (size_t)256 * 128 * 2;
    f16*  Wt_n    = (f16*)p;  p += (size_t)512 * 256 * 2;
    f16*  Wt_ee2  = (f16*)p;  p += (size_t)64 * 192 * 2;
    int*  csr_ptr = (int*)p;  p += (size_t)(NN + 8) * 4;
    int*  csr_row = (int*)p;  p += (size_t)2 * EE * 4;
    int*  cnt     = (int*)p;  p += (size_t)NN * 4;
    int*  cur     = (int*)p;  p += (size_t)NN * 4;

    // ---- one-time: state init, weight conversion, CSR ----
    cvt_kernel<<<(NN * 64 / 2 + 255) / 256, 256, 0, stream>>>(h_t0, ht16, NN * 64 / 2);
    cvt_kernel<<<(EE * 64 / 2 + 255) / 256, 256, 0, stream>>>(h_s0, hs16, EE * 64 / 2);
    cvt_kernel<<<(NN * 128 / 2 + 255) / 256, 256, 0, stream>>>(h_n0, hn16, NN * 128 / 2);
    hipMemcpyAsync(ct, c_t0, (size_t)NN * 64 * 4, hipMemcpyDeviceToDevice, stream);
    hipMemcpyAsync(cs, c_s0, (size_t)EE * 64 * 4, hipMemcpyDeviceToDevice, stream);
    hipMemcpyAsync(cn, c_n0, (size_t)NN * 128 * 4, hipMemcpyDeviceToDevice, stream);

    transpose_w_kernel<<<(256 * 128 + 255) / 256, 256, 0, stream>>>(t_Wih, t_Whh, Wt_t, 64, 128, 256);
    transpose_w_kernel<<<(256 * 128 + 255) / 256, 256, 0, stream>>>(s_Wih, s_Whh, Wt_s, 64, 128, 256);
    transpose_w_kernel<<<(512 * 256 + 255) / 256, 256, 0, stream>>>(n_Wih, n_Whh, Wt_n, 128, 256, 512);
    transpose_ee2_kernel<<<(64 * 192 + 255) / 256, 256, 0, stream>>>(ee_w, Wt_ee2);

    hipMemsetAsync(cnt, 0, NN * sizeof(int), stream);
    hipMemsetAsync(cur, 0, NN * sizeof(int), stream);
    count_kernel<<<(2 * EE) / 256, 256, 0, stream>>>(inc, cnt);
    scan_kernel<<<1, 1024, 0, stream>>>(cnt, csr_ptr);
    fill_kernel<<<(2 * EE) / 256, 256, 0, stream>>>(inc, csr_ptr, cur, csr_row);
    sort_csr_kernel<<<NN / 256, 256, 0, stream>>>(csr_ptr, csr_row);

    const int edgeGrid = NN / 128 + EE / 128;   // 256 + 1024 = 1280

    for (int st = 0; st < S_LEN; ++st) {
        const float* xt = data_tE + (size_t)st * NN * 2;
        const float* xs = data_sE + (size_t)st * EE * 2;
        const float* xn = data_nodes + (size_t)st * NN;

        edge_lstm_fused<<<edgeGrid, 256, 0, stream>>>(
            xt, xs, t_enc_w, t_enc_b, s_enc_w, s_enc_b,
            Wt_t, Wt_s, t_b, s_b, ht16, ct, hs16, cs);
        gather_embed<<<NN / 64, 256, 0, stream>>>(
            xn, ht16, hs16, csr_ptr, csr_row,
            n_enc_w, n_enc_b, Wt_ee2, ee_b, xnode16);
        node_lstm<<<NN / 128, 512, 0, stream>>>(
            xnode16, Wt_n, n_b, out_w, out_b, hn16, cn,
            out + (size_t)st * NN);
    }
}